// Round 13
// baseline (548.284 us; speedup 1.0000x reference)
//
#include <hip/hip_runtime.h>
#include <hip/hip_bf16.h>

// ---------------------------------------------------------------------------
// MiniTransformer: B=8,S=2048,D=1024,H=2048, fp32 in/out, bf16 MFMA inside.
// GEMM: R12 ring schedule (2 barriers/K-tile), 256x256 tile, BK=64, 8 waves
// (2Mx4N), 2-dbuf LDS (128KB).
// R13 change (single variable vs R12): MFMA shape 16x16x32 -> 32x32x16
// (2382 vs 2176 TF ceiling, -13% cy; halves MFMA issue slots).
// Per wave: 4 row-tiles x 2 col-tiles of 32x32, K-steps of 16 (4/K-tile).
// Frag layout: A row=lane&31, k=(lane>>5)*8+j (analog of verified 16x16
// mapping); C/D col=lane&31, row=(reg&3)+8*(reg>>2)+4*(lane>>5) [m74/m101].
// Phase structure unchanged: ph1 A01xB0 | ph2 A01xB1 | BAR | ph3 A23xB1 |
// ph4 A23xB0 | vmcnt(4)+BAR. Staging ring + XOR LDS layout identical
// (read slot (2ks+hi1)^(row&7) stays uniform 8 dword/bank = conflict-free).
// Pipeline: cvt, QKV, scores, cvtW, softmax, PV, LN1, FF1, FF2, LN2.
// Scratch 234,881,024 B.
// ---------------------------------------------------------------------------

typedef __attribute__((ext_vector_type(4))) float   f32x4;
typedef __attribute__((ext_vector_type(16))) float  f32x16;
typedef __attribute__((ext_vector_type(8))) short   short8;
typedef __attribute__((ext_vector_type(4))) short   short4v;
typedef __attribute__((ext_vector_type(8))) __bf16  bf16x8;
typedef unsigned short ushort_t;

static __device__ __forceinline__ unsigned short f2bf(float f) {
  unsigned u = __builtin_bit_cast(unsigned, f);
  u += 0x7fffu + ((u >> 16) & 1u);  // RNE
  return (unsigned short)(u >> 16);
}
static __device__ __forceinline__ float bf2f(unsigned short u) {
  return __builtin_bit_cast(float, (unsigned)u << 16);
}

#define GLDS16(g, l)                                                        \
  __builtin_amdgcn_global_load_lds(                                         \
      (const __attribute__((address_space(1))) void*)(g),                   \
      (__attribute__((address_space(3))) void*)(l), 16, 0, 0)

// ---------------------------------------------------------------------------
__global__ __launch_bounds__(256) void cvt_f32_bf16(
    const float* __restrict__ in, ushort_t* __restrict__ out, long n) {
  long i = ((long)blockIdx.x * 256 + threadIdx.x) * 8;
  if (i >= n) return;
  f32x4 a = *(const f32x4*)(in + i);
  f32x4 b = *(const f32x4*)(in + i + 4);
  short8 t;
  t[0] = (short)f2bf(a.x); t[1] = (short)f2bf(a.y);
  t[2] = (short)f2bf(a.z); t[3] = (short)f2bf(a.w);
  t[4] = (short)f2bf(b.x); t[5] = (short)f2bf(b.y);
  t[6] = (short)f2bf(b.z); t[7] = (short)f2bf(b.w);
  *(short8*)(out + i) = t;
}

// ---------------------------------------------------------------------------
enum { EP_QKV = 0, EP_BF16 = 1, EP_PV = 2, EP_FF1 = 3, EP_FF2 = 4 };

constexpr long BSDc = 8L * 2048 * 1024;

template <int EPI>
__global__ __launch_bounds__(512, 2) void gemm_bt(
    const ushort_t* __restrict__ A, const ushort_t* __restrict__ B,
    void* __restrict__ C, int N, int K, long sA, long sB, long sC, long sRes,
    const float* __restrict__ bias, const float* __restrict__ res,
    float scale) {
  // [dbuf][half][128 rows x 64 k] per operand: 2*2*16KB*2 = 128KB.
  __shared__ __align__(16) ushort_t As[2][2][8192];
  __shared__ __align__(16) ushort_t Bs[2][2][8192];
  const int tid  = threadIdx.x;
  const int lane = tid & 63;
  const int w    = tid >> 6;        // 0..7
  const int wm   = w >> 2;          // 0..1 : wave row-half (128 rows)
  const int wn   = w & 3;           // 0..3 : wave col group (64 cols)
  const int l31  = lane & 31;
  const int hi1  = lane >> 5;       // 0..1 : 8-elem k-group within K=16
  const int e    = lane & 7;
  const long bz  = blockIdx.z;
  const long m0  = (long)blockIdx.x * 256;
  const long n0  = (long)blockIdx.y * 256;
  const ushort_t* Ab = A + bz * sA;
  const ushort_t* Bb = B + bz * sB;

  // Staging source (inverse of read-side XOR): thread handles phys chunks
  // tid and tid+512 of each 1024-chunk half. row = P>>3, slot = (P&7)^(row&7).
  const int srow = tid >> 3;
  const int sc   = (tid & 7) ^ (srow & 7);
  const long offA0 = (m0 + srow) * (long)K + sc * 8;
  const long offB0 = (n0 + srow) * (long)K + sc * 8;
  const int dst0 = w * 512;
  const int dst1 = 4096 + w * 512;

#define STAGE_A(t, h)                                                       \
  {                                                                         \
    const long o_ = (long)(t) * 64 + (long)(h) * 128 * K;                   \
    ushort_t* l_ = &As[(t) & 1][h][0];                                      \
    GLDS16(Ab + offA0 + o_, l_ + dst0);                                     \
    GLDS16(Ab + offA0 + 64 * (long)K + o_, l_ + dst1);                      \
  }
#define STAGE_B(t, h)                                                       \
  {                                                                         \
    const long o_ = (long)(t) * 64 + (long)(h) * 128 * K;                   \
    ushort_t* l_ = &Bs[(t) & 1][h][0];                                      \
    GLDS16(Bb + offB0 + o_, l_ + dst0);                                     \
    GLDS16(Bb + offB0 + 64 * (long)K + o_, l_ + dst1);                      \
  }

  // Read-side swizzled byte offsets per K-step ks (k = ks*16 + hi1*8 + j):
  // within a 128-row half: addr = row*128 + ((2*ks+hi1)^(row&7))*16,
  // row = tilebase + l31, row&7 == e (tile bases are multiples of 32).
  int sks[4];
#pragma unroll
  for (int ks = 0; ks < 4; ++ks) sks[ks] = (((2 * ks + hi1) ^ e) << 4);

  // A row-tile t (0..3): rows wm*128 + t*32 + l31.
#define READ_A2(tb)                                                         \
  _Pragma("unroll") for (int i = 0; i < 2; ++i)                             \
  _Pragma("unroll") for (int ks = 0; ks < 4; ++ks)                          \
    afr[i][ks] = *(const short8*)(Ah + (((tb) + i) * 32 + l31) * 128 +      \
                                  sks[ks]);
  // B col-tile bj (0..1): cols(b-rows) (wn&1)*64 + bj*32 + l31.
#define READ_B1(bj)                                                         \
  _Pragma("unroll") for (int ks = 0; ks < 4; ++ks)                          \
    bfr[bj][ks] = *(const short8*)(Bh + ((bj) * 32 + l31) * 128 + sks[ks]);

// 8 MFMAs per phase: ks outer, i inner -> same-acc reuse distance 2.
#define QMFMA(ig, jt)                                                       \
  _Pragma("unroll") for (int ks = 0; ks < 4; ++ks)                          \
  _Pragma("unroll") for (int i = 0; i < 2; ++i)                             \
    acc[(ig) * 2 + i][jt] = __builtin_amdgcn_mfma_f32_32x32x16_bf16(        \
        __builtin_bit_cast(bf16x8, afr[i][ks]),                             \
        __builtin_bit_cast(bf16x8, bfr[jt][ks]), acc[(ig) * 2 + i][jt], 0,  \
        0, 0);

  f32x16 acc[4][2] = {};
  const int NT = K >> 6;  // K-tiles of 64 (16 or 32)

  // Prologue ring: (0).B0,B1,A0,A1,(1).B0,B1 = 12 loads; retire tile 0.
  STAGE_B(0, 0) STAGE_B(0, 1) STAGE_A(0, 0) STAGE_A(0, 1)
  STAGE_B(1, 0) STAGE_B(1, 1)
  asm volatile("s_waitcnt vmcnt(4)" ::: "memory");
  __builtin_amdgcn_sched_barrier(0);
  __builtin_amdgcn_s_barrier();
  __builtin_amdgcn_sched_barrier(0);

  for (int u = 0; u < NT; ++u) {
    const int d = u & 1;
    const char* Ah = (const char*)&As[d][wm][0];
    const char* Bh = (const char*)&Bs[d][wn >> 1][0] + (wn & 1) * 8192;
    short8 afr[2][4], bfr[2][4];
    // ---- phase 1: A01 x B0 (no bars: buf d confirmed at entry) ----
    READ_A2(0)
    READ_B1(0)
    if (u + 1 < NT) STAGE_A(u + 1, 0)
    __builtin_amdgcn_s_setprio(1);
    QMFMA(0, 0)
    __builtin_amdgcn_s_setprio(0);
    // ---- phase 2: A01 x B1 ----
    READ_B1(1)
    if (u + 1 < NT) STAGE_A(u + 1, 1)
    __builtin_amdgcn_s_setprio(1);
    QMFMA(0, 1)
    __builtin_amdgcn_s_setprio(0);
    __builtin_amdgcn_s_barrier();  // all waves done reading B-halves of buf d
    // ---- phase 3: A23 x B1 (stage may overwrite buf d B-halves now) ----
    READ_A2(2)
    if (u + 2 < NT) STAGE_B(u + 2, 0)
    __builtin_amdgcn_s_setprio(1);
    QMFMA(1, 1)
    __builtin_amdgcn_s_setprio(0);
    // ---- phase 4: A23 x B0 (all from regs) ----
    if (u + 2 < NT) STAGE_B(u + 2, 1)
    __builtin_amdgcn_s_setprio(1);
    QMFMA(1, 0)
    __builtin_amdgcn_s_setprio(0);
    // ---- K-tile boundary: tile u+1 must be fully resident ----
    if (u + 1 < NT) {
      if (u + 2 < NT) {
        asm volatile("s_waitcnt vmcnt(4)" ::: "memory");
      } else {
        asm volatile("s_waitcnt vmcnt(0)" ::: "memory");
      }
      __builtin_amdgcn_sched_barrier(0);
      __builtin_amdgcn_s_barrier();
      __builtin_amdgcn_sched_barrier(0);
    }
  }
#undef STAGE_A
#undef STAGE_B
#undef READ_A2
#undef READ_B1
#undef QMFMA

  // Epilogue. 32x32 C/D layout: col = lane&31,
  // row = (reg&3) + 8*(reg>>2) + 4*(lane>>5), reg in [0,16).
#pragma unroll
  for (int it = 0; it < 4; ++it) {
#pragma unroll
    for (int jt = 0; jt < 2; ++jt) {
      const long rowb = m0 + wm * 128 + it * 32;
      const long gc   = n0 + wn * 64 + jt * 32 + l31;
#pragma unroll
      for (int q = 0; q < 4; ++q) {
        const long gr0 = rowb + 8 * q + 4 * hi1;  // rows gr0..gr0+3
        if constexpr (EPI == EP_QKV) {
          long which = gc >> 10;  // 0=q, 1=k, 2=v (uniform per block)
          long col   = gc & 1023;
          if (which == 2) {
            long bb = gr0 >> 11, s = gr0 & 2047;
            short4v pk;
#pragma unroll
            for (int r = 0; r < 4; ++r)
              pk[r] = (short)f2bf(acc[it][jt][q * 4 + r]);
            *(short4v*)((ushort_t*)C + 2 * BSDc + ((bb << 10) + col) * 2048 +
                        s) = pk;
          } else {
#pragma unroll
            for (int r = 0; r < 4; ++r)
              ((ushort_t*)C)[which * BSDc + (gr0 + r) * 1024 + col] =
                  f2bf(acc[it][jt][q * 4 + r]);
          }
        } else {
#pragma unroll
          for (int r = 0; r < 4; ++r) {
            long gm = gr0 + r;
            float v = acc[it][jt][q * 4 + r] * scale;
            if constexpr (EPI == EP_BF16) {
              ((ushort_t*)C)[bz * sC + gm * N + gc] = f2bf(v);
            } else if constexpr (EPI == EP_PV) {
              v += res[bz * sRes + gm * N + gc];
              ((float*)C)[bz * sC + gm * N + gc] = v;
            } else if constexpr (EPI == EP_FF1) {
              v += bias[gc];
              v = v > 0.f ? v : 0.f;
              ((ushort_t*)C)[gm * N + gc] = f2bf(v);
            } else {  // EP_FF2
              v += bias[gc] + res[gm * N + gc];
              ((float*)C)[gm * N + gc] = v;
            }
          }
        }
      }
    }
  }
}

// ---------------------------------------------------------------------------
__global__ __launch_bounds__(256) void softmax_inplace(
    ushort_t* __restrict__ P) {
  __shared__ float rmax[4], rsum[4];
  const int tid   = threadIdx.x;
  const long base = (long)blockIdx.x * 2048;
  short8 sv = *(const short8*)(P + base + tid * 8);
  float v[8];
#pragma unroll
  for (int j = 0; j < 8; ++j) v[j] = bf2f((unsigned short)sv[j]);
  float mx = v[0];
#pragma unroll
  for (int j = 1; j < 8; ++j) mx = fmaxf(mx, v[j]);
#pragma unroll
  for (int off = 32; off; off >>= 1) mx = fmaxf(mx, __shfl_down(mx, off, 64));
  if ((tid & 63) == 0) rmax[tid >> 6] = mx;
  __syncthreads();
  mx = fmaxf(fmaxf(rmax[0], rmax[1]), fmaxf(rmax[2], rmax[3]));
  float s = 0.f;
#pragma unroll
  for (int j = 0; j < 8; ++j) {
    v[j] = __expf(v[j] - mx);
    s += v[j];
  }
#pragma unroll
  for (int off = 32; off; off >>= 1) s += __shfl_down(s, off, 64);
  if ((tid & 63) == 0) rsum[tid >> 6] = s;
  __syncthreads();
  s = (rsum[0] + rsum[1]) + (rsum[2] + rsum[3]);
  float inv = 1.f / s;
  short8 o;
#pragma unroll
  for (int j = 0; j < 8; ++j) o[j] = (short)f2bf(v[j] * inv);
  *(short8*)(P + base + tid * 8) = o;
}

// ---------------------------------------------------------------------------
template <int MODE>
__global__ __launch_bounds__(256) void ln_row(const float* __restrict__ X,
                                              const float* __restrict__ g,
                                              const float* __restrict__ be,
                                              float* __restrict__ Yf,
                                              ushort_t* __restrict__ Yb) {
  __shared__ float rs[4], rq[4];
  const int tid   = threadIdx.x;
  const long base = (long)blockIdx.x << 10;
  f32x4 v = *(const f32x4*)(X + base + tid * 4);
  float s = v.x + v.y + v.z + v.w;
  float q = v.x * v.x + v.y * v.y + v.z * v.z + v.w * v.w;
#pragma unroll
  for (int off = 32; off; off >>= 1) {
    s += __shfl_down(s, off, 64);
    q += __shfl_down(q, off, 64);
  }
  if ((tid & 63) == 0) {
    rs[tid >> 6] = s;
    rq[tid >> 6] = q;
  }
  __syncthreads();
  s = (rs[0] + rs[1]) + (rs[2] + rs[3]);
  q = (rq[0] + rq[1]) + (rq[2] + rq[3]);
  float mu   = s * (1.f / 1024.f);
  float var  = q * (1.f / 1024.f) - mu * mu;
  float rstd = rsqrtf(var + 1e-5f);
  int c    = tid * 4;
  f32x4 gg = *(const f32x4*)(g + c);
  f32x4 bb = *(const f32x4*)(be + c);
  f32x4 y;
  y.x = (v.x - mu) * rstd * gg.x + bb.x;
  y.y = (v.y - mu) * rstd * gg.y + bb.y;
  y.z = (v.z - mu) * rstd * gg.z + bb.z;
  y.w = (v.w - mu) * rstd * gg.w + bb.w;
  *(f32x4*)(Yf + base + c) = y;
  if constexpr (MODE == 0) {
    short4v ob;
    ob[0] = (short)f2bf(y.x);
    ob[1] = (short)f2bf(y.y);
    ob[2] = (short)f2bf(y.z);
    ob[3] = (short)f2bf(y.w);
    *(short4v*)(Yb + base + c) = ob;
  }
}

// ---------------------------------------------------------------------------
extern "C" void kernel_launch(void* const* d_in, const int* in_sizes, int n_in,
                              void* d_out, int out_size, void* d_ws,
                              size_t ws_size, hipStream_t stream) {
  const float* x   = (const float*)d_in[0];
  const float* Wq  = (const float*)d_in[1];
  const float* Wk  = (const float*)d_in[2];
  const float* Wv  = (const float*)d_in[3];
  const float* W1  = (const float*)d_in[4];
  const float* b1  = (const float*)d_in[5];
  const float* W2  = (const float*)d_in[6];
  const float* b2  = (const float*)d_in[7];
  const float* g1  = (const float*)d_in[8];
  const float* be1 = (const float*)d_in[9];
  const float* g2  = (const float*)d_in[10];
  const float* be2 = (const float*)d_in[11];
  float* out = (float*)d_out;

  constexpr long BSD = 8L * 2048 * 1024;
  constexpr long BSS = 8L * 2048 * 2048;
  constexpr long DD  = 1024L * 1024;
  constexpr long HD  = 2048L * 1024;

  // Scratch: qb | kb | vTb | sP | r1  = 234,881,024 bytes total.
  ushort_t* qb  = (ushort_t*)d_ws;
  ushort_t* kb  = qb + BSD;
  ushort_t* vTb = kb + BSD;
  ushort_t* sP  = vTb + BSD;
  float*    r1  = (float*)(sP + BSS);

  ushort_t* xb    = sP;              // dead before scores written
  ushort_t* Wqkvb = (ushort_t*)r1;   // dead before PV writes r1
  ushort_t* W1b   = kb;              // converted after scores GEMM
  ushort_t* W2b   = kb + HD;
  ushort_t* hb    = qb;
  float*    h     = out;             // d_out dead until LN2 rewrites it

  dim3 blk(256), gblk(512);
  const long SD = 2048L * 1024, SS = 2048L * 2048, DS = 1024L * 2048;

  // 0: conversions
  cvt_f32_bf16<<<dim3(8192), blk, 0, stream>>>(x, xb, BSD);
  cvt_f32_bf16<<<dim3(512), blk, 0, stream>>>(Wq, Wqkvb, DD);
  cvt_f32_bf16<<<dim3(512), blk, 0, stream>>>(Wk, Wqkvb + DD, DD);
  cvt_f32_bf16<<<dim3(512), blk, 0, stream>>>(Wv, Wqkvb + 2 * DD, DD);
  // 1: fused QKV projection (M=16384, N=3072, K=1024)
  gemm_bt<EP_QKV><<<dim3(64, 12, 1), gblk, 0, stream>>>(
      xb, Wqkvb, qb, 3072, 1024, 0, 0, 0, 0, nullptr, nullptr, 1.f);
  // 2: scores = q@k^T / 32 (per batch: M=N=2048, K=1024)
  gemm_bt<EP_BF16><<<dim3(8, 8, 8), gblk, 0, stream>>>(
      qb, kb, sP, 2048, 1024, SD, SD, SS, 0, nullptr, nullptr, 0.03125f);
  // 2b: FFN weights into kb region (kb dead now)
  cvt_f32_bf16<<<dim3(1024), blk, 0, stream>>>(W1, W1b, HD);
  cvt_f32_bf16<<<dim3(1024), blk, 0, stream>>>(W2, W2b, HD);
  // 3: softmax
  softmax_inplace<<<dim3(16384), blk, 0, stream>>>(sP);
  // 4: attn_out + x (per batch: M=2048, N=1024, K=2048)
  gemm_bt<EP_PV><<<dim3(8, 4, 8), gblk, 0, stream>>>(
      sP, vTb, r1, 1024, 2048, SS, DS, SD, SD, nullptr, x, 1.f);
  // 5: LN1 -> h (fp32, in d_out) + hb (bf16, aliases qb)
  ln_row<0><<<dim3(16384), blk, 0, stream>>>(r1, g1, be1, h, hb);
  // 6: ff1 = relu(hb@W1^T + b1) (M=16384, N=2048, K=1024)
  gemm_bt<EP_FF1><<<dim3(64, 8, 1), gblk, 0, stream>>>(
      hb, W1b, sP, 2048, 1024, 0, 0, 0, 0, b1, nullptr, 1.f);
  // 7: res2 = ff1@W2^T + b2 + h (M=16384, N=1024, K=2048)
  gemm_bt<EP_FF2><<<dim3(64, 4, 1), gblk, 0, stream>>>(
      sP, W2b, r1, 1024, 2048, 0, 0, 0, 0, b2, h, 1.f);
  // 8: LN2 -> out (overwrites h)
  ln_row<1><<<dim3(16384), blk, 0, stream>>>(r1, g2, be2, out, nullptr);
}